// Round 1
// baseline (895.665 us; speedup 1.0000x reference)
//
#include <hip/hip_runtime.h>
#include <math.h>

// Soft-DTW forward, B=128, N=M=512, gamma=1.0, fp32.
// Baseline: anti-diagonal wavefront. 1 block per batch, 1 thread per column,
// 3 rotating diagonals in LDS, one __syncthreads per diagonal (1023 total).
// Critical path = 1023 dependent softmin steps (structural).

#define BB 128
#define NN 512
#define MM 512

__launch_bounds__(MM, 1)
__global__ void softdtw_diag(const float* __restrict__ D, float* __restrict__ out) {
    const int b = blockIdx.x;
    const int j = threadIdx.x;                    // column 0..M-1
    const float* __restrict__ Db = D + (size_t)b * (NN * MM);

    __shared__ float bufA[MM];
    __shared__ float bufB[MM];
    __shared__ float bufC[MM];

    float* d2prev = bufA;   // diagonal s-2
    float* d1prev = bufB;   // diagonal s-1
    float* dcur   = bufC;   // diagonal s (write target)

    const float INF = INFINITY;
    // per-thread pointer into D: first active step is s=j (i=0), addr = j;
    // advances by MM each active step (row i increments).
    const float* dptr = Db + j;

    for (int s = 0; s < NN + MM - 1; ++s) {
        const int i = s - j;
        const bool active = (i >= 0) && (i < NN);
        if (active) {
            float diag, up, left;
            if (i == 0) {
                diag = (j == 0) ? 0.0f : INF;
                up   = INF;
            } else {
                up   = d1prev[j];
                diag = (j == 0) ? INF : d2prev[j - 1];
            }
            left = (j == 0) ? INF : d1prev[j - 1];

            const float mn = fminf(diag, fminf(up, left));
            // gamma = 1: softmin = mn - log(sum exp(mn - x))
            const float e = __expf(mn - diag) + __expf(mn - up) + __expf(mn - left);
            const float nv = *dptr + mn - __logf(e);
            dptr += MM;
            dcur[j] = nv;
        }
        __syncthreads();
        // rotate diagonals
        float* t = d2prev;
        d2prev = d1prev;
        d1prev = dcur;
        dcur   = t;
    }

    // Final cell (i=N-1, j=M-1) was written on the last diagonal, which after
    // the final rotation lives in d1prev.
    if (j == MM - 1) out[b] = d1prev[MM - 1];
}

extern "C" void kernel_launch(void* const* d_in, const int* in_sizes, int n_in,
                              void* d_out, int out_size, void* d_ws, size_t ws_size,
                              hipStream_t stream) {
    const float* D = (const float*)d_in[0];
    float* out = (float*)d_out;
    softdtw_diag<<<BB, MM, 0, stream>>>(D, out);
}

// Round 3
// 841.855 us; speedup vs baseline: 1.0639x; 1.0639x over previous
//
#include <hip/hip_runtime.h>

// Soft-DTW forward, B=128, N=M=512, gamma=1.0, fp32.
// One wave (64 lanes) per batch element. Lane k owns columns 8k..8k+7.
// Anti-diagonal wavefront entirely in registers: r1 = diag s-1, r2 = diag s-2.
// Cross-lane handoff: one __shfl_up per step (second value reuses last step's).
// D staged through a double-buffered register window (two float4 loads/step,
// prefetched 8 steps ahead) -> global latency off the dependency chain.
// R is kept scaled by log2(e): softmin' = mn - log2(1 + 2^(mn-med) + 2^(mn-max))
// (the min term is exactly 2^0=1 -> only 2 exp2 + 1 log2 per cell).
// NOTE: use __builtin_amdgcn_exp2f / __builtin_amdgcn_logf (v_exp_f32 =
// 2^x, v_log_f32 = log2) — the __exp2f/__log2f names collide with glibc
// math.h macros on this toolchain.

#define BB 128
#define NN 512
#define MM 512
#define INFF __builtin_inff()

__device__ __forceinline__ float fmin3(float a, float b, float c) {
    return __builtin_fminf(__builtin_fminf(a, b), c);
}
__device__ __forceinline__ float fmax3(float a, float b, float c) {
    return __builtin_fmaxf(__builtin_fmaxf(a, b), c);
}

template<bool PH1>
__device__ __forceinline__ void phase_loop(int qbase,
    const float* __restrict__ Db, int k, int jb,
    float (&r1)[8], float (&r2)[8], float4 (&buf)[2][8][2],
    int& irow, int& eoff, float& shprev)
{
    #pragma unroll 1
    for (int qq = 0; qq < 32; ++qq) {
        const int q = qbase + qq;
        #pragma unroll
        for (int p = 0; p < 2; ++p) {
            #pragma unroll
            for (int u = 0; u < 8; ++u) {
                const int s = q * 16 + p * 8 + u;

                // lane k-1's r1[7]/r2[7] as of start of this step.
                // sh2(s) == sh1(s-1) because r2[7] <- r1[7] each rotation.
                const float sh1 = __shfl_up(r1[7], 1, 64);
                const float sh2 = shprev;

                // prefetch window s+8 (row irow = s+8-jb, cols jb..jb+7)
                // into buf[p^1][u]; its old occupant's last use was step s-1.
                if ((unsigned)irow < (unsigned)NN) {
                    const float4* lp = (const float4*)(Db + eoff);
                    buf[p ^ 1][u][0] = lp[0];
                    buf[p ^ 1][u][1] = lp[1];
                }
                irow += 1;
                eoff += MM;

                float nv[8];
                #pragma unroll
                for (int c = 0; c < 8; ++c) {
                    // cell (i = s-jb-c, j = jb+c)
                    float up_ = r1[c];                       // (i-1, j)
                    float lf  = (c == 0) ? sh1 : r1[c - 1];  // (i,   j-1)
                    float dg  = (c == 0) ? sh2 : r2[c - 1];  // (i-1, j-1)
                    if (c == 0) {                            // j==0 boundary
                        lf = (k == 0) ? INFF : lf;
                        dg = (k == 0) ? INFF : dg;
                    }
                    if (PH1 && c == u) {                     // i==0 boundary (j==s)
                        const bool edge = (k == (2 * q + p));
                        up_ = edge ? INFF : up_;
                        const float dedge = (s == 0) ? 0.0f : INFF;
                        dg = edge ? dedge : dg;
                    }

                    // D element: window w = s-c, element c
                    const int par  = (c <= u) ? p : (p ^ 1);
                    const int slot = (c <= u) ? (u - c) : (8 + u - c);
                    const float4 f4 = buf[par][slot][c >> 2];
                    const float d = ((c & 3) == 0) ? f4.x :
                                    ((c & 3) == 1) ? f4.y :
                                    ((c & 3) == 2) ? f4.z : f4.w;

                    const float mn = fmin3(dg, up_, lf);                 // v_min3
                    const float md = __builtin_amdgcn_fmed3f(dg, up_, lf);
                    const float mx = fmax3(dg, up_, lf);                 // v_max3
                    const float e  = 1.0f + __builtin_amdgcn_exp2f(mn - md)
                                          + __builtin_amdgcn_exp2f(mn - mx);
                    const float l  = __builtin_amdgcn_logf(e);           // log2
                    nv[c] = __builtin_fmaf(d, 1.4426950408889634f, mn - l);
                }

                shprev = sh1;

                // rotate + hold inactive columns (preserves final answer too)
                #pragma unroll
                for (int c = 0; c < 8; ++c) {
                    const bool act = PH1 ? ((jb + c) <= s)
                                         : ((jb + c) >= (s - (NN - 1)));
                    r2[c] = r1[c];
                    r1[c] = act ? nv[c] : r1[c];
                }
            }
        }
    }
}

__launch_bounds__(64, 1)
__global__ void softdtw_wave(const float* __restrict__ D, float* __restrict__ out) {
    const int b = blockIdx.x;
    const int k = threadIdx.x & 63;
    const int jb = k << 3;
    const float* __restrict__ Db = D + (size_t)b * (NN * MM);

    float r1[8], r2[8];
    float4 buf[2][8][2];
    #pragma unroll
    for (int c = 0; c < 8; ++c) { r1[c] = INFF; r2[c] = INFF; }
    #pragma unroll
    for (int p = 0; p < 2; ++p)
        #pragma unroll
        for (int w = 0; w < 8; ++w) {
            buf[p][w][0] = make_float4(0.f, 0.f, 0.f, 0.f);
            buf[p][w][1] = make_float4(0.f, 0.f, 0.f, 0.f);
        }

    // prologue: windows 0..7 (rows w-jb; only lane 0 in range) into buf[0][w]
    #pragma unroll
    for (int w = 0; w < 8; ++w) {
        const int i0 = w - jb;
        if ((unsigned)i0 < (unsigned)NN) {
            const float4* lp = (const float4*)(Db + i0 * MM + jb);
            buf[0][w][0] = lp[0];
            buf[0][w][1] = lp[1];
        }
    }

    int irow = 8 - jb;            // row of window s+8 at s=0
    int eoff = irow * MM + jb;    // element offset of that window
    float shprev = INFF;

    phase_loop<true >(0,  Db, k, jb, r1, r2, buf, irow, eoff, shprev);
    phase_loop<false>(32, Db, k, jb, r1, r2, buf, irow, eoff, shprev);

    // R'[N,M] sits in lane 63's r1[7]; unscale from log2e domain.
    if (k == 63) out[b] = r1[7] * 0.6931471805599453f;
}

extern "C" void kernel_launch(void* const* d_in, const int* in_sizes, int n_in,
                              void* d_out, int out_size, void* d_ws, size_t ws_size,
                              hipStream_t stream) {
    const float* D = (const float*)d_in[0];
    float* out = (float*)d_out;
    softdtw_wave<<<BB, 64, 0, stream>>>(D, out);
}

// Round 4
// 388.171 us; speedup vs baseline: 2.3074x; 2.1688x over previous
//
#include <hip/hip_runtime.h>

// Soft-DTW forward, B=128, N=M=512, gamma=1.0, fp32.
// One wave per batch element; lane k owns columns 8k..8k+7; anti-diagonal
// wavefront entirely in registers (r1 = diag s-1, r2 = diag s-2).
//
// Round-4 changes (post-mortem of 709us round-3):
//  * UNCONDITIONAL clamped-row prefetch loads -> static vmem count ->
//    compiler can emit pipelined s_waitcnt vmcnt(N) instead of vmcnt(0)
//    every step (the round-3 killer: exec-masked loads made the count
//    dynamic, serializing ~900cyc gather latency into each step).
//  * __shfl_up issued at END of previous step, consumed LAST (cell c=0
//    computed after c=7..1) -> permute latency hidden.
//  * INF replaced by BIG=1e30f sentinel: fake cells (i<0) stay exactly
//    1e30 (fp32 absorption), exp2(x-1e30)==0 exactly, so no per-cell
//    activity masking is needed at all; post-active junk (i>=N) provably
//    never feeds a valid cell; final cell is written on the last step.
//  * Only special cases left: lane0 j=0 boundary (2 cndmask) and the
//    (0,0) diag=0 seed via x0 (0 -> BIG after step 0).
// R carried scaled by log2(e): softmin' = mn - log2(1 + 2^(mn-md) + 2^(mn-mx)).

#define BB 128
#define NN 512
#define MM 512
#define BIGF 1e30f
#define L2E  1.4426950408889634f

template<int P, int U>
__device__ __forceinline__ void dostep(
    const float* __restrict__ Db, int k, int jb,
    float (&r1)[8], float (&r2)[8], float4 (&buf)[2][8][2],
    int& irow, float& sh, float& shprev, float& x0)
{
    // prefetch window s+8 (row irow, clamped) into buf[P^1][U] — UNCONDITIONAL
    {
        const int r = irow < 0 ? 0 : (irow > NN - 1 ? NN - 1 : irow); // v_med3
        const float4* lp = (const float4*)(Db + ((r << 9) + jb));
        buf[P ^ 1][U][0] = lp[0];
        buf[P ^ 1][U][1] = lp[1];
        irow += 1;
    }

    float nv[8];
    #pragma unroll
    for (int cc = 7; cc >= 0; --cc) {   // c=0 LAST: it alone waits on the shfl
        const int c = cc;
        float up_, lf, dg;
        up_ = r1[c];
        if (c == 0) {
            lf = (k == 0) ? BIGF : sh;
            dg = (k == 0) ? x0   : shprev;
        } else {
            lf = r1[c - 1];
            dg = r2[c - 1];
        }
        const int par  = (c <= U) ? P : (P ^ 1);
        const int slot = (c <= U) ? (U - c) : (8 + U - c);
        const float4 f4 = buf[par][slot][c >> 2];
        const float d = ((c & 3) == 0) ? f4.x :
                        ((c & 3) == 1) ? f4.y :
                        ((c & 3) == 2) ? f4.z : f4.w;

        const float mn = __builtin_fminf(__builtin_fminf(dg, up_), lf); // v_min3
        const float md = __builtin_amdgcn_fmed3f(dg, up_, lf);
        const float mx = __builtin_fmaxf(__builtin_fmaxf(dg, up_), lf); // v_max3
        const float e  = 1.0f + __builtin_amdgcn_exp2f(mn - md)
                              + __builtin_amdgcn_exp2f(mn - mx);
        nv[c] = __builtin_fmaf(d, L2E, mn - __builtin_amdgcn_logf(e));
    }

    x0 = BIGF;
    #pragma unroll
    for (int c = 0; c < 8; ++c) { r2[c] = r1[c]; r1[c] = nv[c]; }
    shprev = sh;
    sh = __shfl_up(r1[7], 1, 64);   // for NEXT step; ~full step of slack
}

#define STEP8A(DB) \
    dostep<0,0>(DB,k,jb,r1,r2,buf,irow,sh,shprev,x0); \
    dostep<0,1>(DB,k,jb,r1,r2,buf,irow,sh,shprev,x0); \
    dostep<0,2>(DB,k,jb,r1,r2,buf,irow,sh,shprev,x0); \
    dostep<0,3>(DB,k,jb,r1,r2,buf,irow,sh,shprev,x0); \
    dostep<0,4>(DB,k,jb,r1,r2,buf,irow,sh,shprev,x0); \
    dostep<0,5>(DB,k,jb,r1,r2,buf,irow,sh,shprev,x0); \
    dostep<0,6>(DB,k,jb,r1,r2,buf,irow,sh,shprev,x0); \
    dostep<0,7>(DB,k,jb,r1,r2,buf,irow,sh,shprev,x0);

#define STEP8B(DB) \
    dostep<1,0>(DB,k,jb,r1,r2,buf,irow,sh,shprev,x0); \
    dostep<1,1>(DB,k,jb,r1,r2,buf,irow,sh,shprev,x0); \
    dostep<1,2>(DB,k,jb,r1,r2,buf,irow,sh,shprev,x0); \
    dostep<1,3>(DB,k,jb,r1,r2,buf,irow,sh,shprev,x0); \
    dostep<1,4>(DB,k,jb,r1,r2,buf,irow,sh,shprev,x0); \
    dostep<1,5>(DB,k,jb,r1,r2,buf,irow,sh,shprev,x0); \
    dostep<1,6>(DB,k,jb,r1,r2,buf,irow,sh,shprev,x0); \
    dostep<1,7>(DB,k,jb,r1,r2,buf,irow,sh,shprev,x0);

__launch_bounds__(64, 1)
__global__ void softdtw_wave(const float* __restrict__ D, float* __restrict__ out) {
    const int b = blockIdx.x;
    const int k = threadIdx.x & 63;
    const int jb = k << 3;
    const float* __restrict__ Db = D + (size_t)b * (NN * MM);

    float r1[8], r2[8];
    float4 buf[2][8][2];
    #pragma unroll
    for (int c = 0; c < 8; ++c) { r1[c] = BIGF; r2[c] = BIGF; }
    // init buf: buf[1][1..7] is READ at steps 0..6 before being written
    // (feeds fake cells only, but must be finite — NaN would propagate).
    #pragma unroll
    for (int p = 0; p < 2; ++p)
        #pragma unroll
        for (int w = 0; w < 8; ++w) {
            buf[p][w][0] = make_float4(0.f, 0.f, 0.f, 0.f);
            buf[p][w][1] = make_float4(0.f, 0.f, 0.f, 0.f);
        }

    // prologue: windows 0..7 (row w-jb, clamped) into buf[0][w] — unconditional
    #pragma unroll
    for (int w = 0; w < 8; ++w) {
        const int i0 = w - jb;
        const int r = i0 < 0 ? 0 : (i0 > NN - 1 ? NN - 1 : i0);
        const float4* lp = (const float4*)(Db + ((r << 9) + jb));
        buf[0][w][0] = lp[0];
        buf[0][w][1] = lp[1];
    }

    int irow = 8 - jb;          // row of window s+8 at s=0
    float sh = BIGF, shprev = BIGF, x0 = 0.0f;

    // 63 x 16 = 1008 steps
    #pragma unroll 1
    for (int qq = 0; qq < 63; ++qq) {
        STEP8A(Db)
        STEP8B(Db)
    }
    // tail: steps 1008..1022 (15 steps; parity continues: P=0 block then 7 of P=1)
    STEP8A(Db)
    dostep<1,0>(Db,k,jb,r1,r2,buf,irow,sh,shprev,x0);
    dostep<1,1>(Db,k,jb,r1,r2,buf,irow,sh,shprev,x0);
    dostep<1,2>(Db,k,jb,r1,r2,buf,irow,sh,shprev,x0);
    dostep<1,3>(Db,k,jb,r1,r2,buf,irow,sh,shprev,x0);
    dostep<1,4>(Db,k,jb,r1,r2,buf,irow,sh,shprev,x0);
    dostep<1,5>(Db,k,jb,r1,r2,buf,irow,sh,shprev,x0);
    dostep<1,6>(Db,k,jb,r1,r2,buf,irow,sh,shprev,x0);

    // R'[N-1,M-1] = lane 63's r1[7], written at the final step; unscale.
    if (k == 63) out[b] = r1[7] * 0.6931471805599453f;
}

extern "C" void kernel_launch(void* const* d_in, const int* in_sizes, int n_in,
                              void* d_out, int out_size, void* d_ws, size_t ws_size,
                              hipStream_t stream) {
    const float* D = (const float*)d_in[0];
    float* out = (float*)d_out;
    softdtw_wave<<<BB, 64, 0, stream>>>(D, out);
}